// Round 7
// baseline (408.497 us; speedup 1.0000x reference)
//
#include <hip/hip_runtime.h>

#define B_ 4
#define C_ 64
#define F_ 128
#define T_ 128
#define K_ 8
#define H_ 32
#define S_ 121   // T - K + 1
#define N_ 512   // B * F
#define G_ 128   // 4 * H
#define CK_ 512  // C * K

typedef __attribute__((ext_vector_type(8))) short short8;
typedef __attribute__((ext_vector_type(4))) float f32x4;
typedef __attribute__((ext_vector_type(2))) float f32x2;
typedef __attribute__((ext_vector_type(2))) unsigned int ui2;
union FragU { uint4 u; short8 s; };

__device__ __forceinline__ unsigned int pk2(float a, float b){   // RNE f32->bf16 pair
  unsigned int ua = __float_as_uint(a); ua += 0x7fffu + ((ua>>16)&1u);
  unsigned int ub = __float_as_uint(b); ub += 0x7fffu + ((ub>>16)&1u);
  return (ua>>16) | (ub & 0xffff0000u);
}
__device__ __forceinline__ unsigned short bfu(float a){          // RNE f32->bf16
  unsigned int ua = __float_as_uint(a); ua += 0x7fffu + ((ua>>16)&1u);
  return (unsigned short)(ua>>16);
}

// ---------------------------------------------------------------- instance norm stats
__global__ __launch_bounds__(256) void k_norm(const float* __restrict__ x,
    const float* __restrict__ gamma, const float* __restrict__ beta,
    float* __restrict__ scale, float* __restrict__ shift){
  int bc = blockIdx.x;
  const float* p = x + (size_t)bc * (F_*T_);
  float s = 0.f, q = 0.f;
  for (int i = threadIdx.x; i < F_*T_; i += 256){ float v = p[i]; s += v; q += v*v; }
  #pragma unroll
  for (int o = 32; o; o >>= 1){ s += __shfl_down(s, o); q += __shfl_down(q, o); }
  __shared__ float ss[4], qq[4];
  int w = threadIdx.x >> 6;
  if ((threadIdx.x & 63) == 0){ ss[w] = s; qq[w] = q; }
  __syncthreads();
  if (threadIdx.x == 0){
    s = ss[0]+ss[1]+ss[2]+ss[3]; q = qq[0]+qq[1]+qq[2]+qq[3];
    float mu  = s / (float)(F_*T_);
    float var = q / (float)(F_*T_) - mu*mu;
    if (var < 0.f) var = 0.f;
    int c = bc & (C_-1);
    float sc = gamma[c] * rsqrtf(var + 1e-5f);
    scale[bc] = sc;
    shift[bc] = beta[c] - mu * sc;
  }
}

// ---------------------------------------------------------------- weight f32 -> bf16
__global__ __launch_bounds__(256) void k_wcvt(const float* __restrict__ a,
    unsigned short* __restrict__ o, int nel){
  int i = blockIdx.x*256 + threadIdx.x;
  if (i < nel) o[i] = bfu(a[i]);
}
// conv weights: bf16 + reverse k within each 8-block (absorbs conv flip into GEMM)
__global__ __launch_bounds__(256) void k_wrev(const float* __restrict__ a,
    unsigned short* __restrict__ o, int nel){
  int i = blockIdx.x*256 + threadIdx.x;
  if (i < nel){ int j = (i & ~7) | (7 - (i & 7)); o[i] = bfu(a[j]); }
}

// ---------------------------------------------------------------- fused LSTM stack (layers 0..3)
// Round-12: round-6's fused layer-0 GEMM spilled (VGPR 256, WRITE_SIZE 8->70MB
// = scratch traffic in the hot kb loop). Fix: per-stl GEMM passes (acc[8]=32
// VGPR not 64, one A-frag not two), unroll-disabled so the two passes never
// interleave. Same per-(stl,gt) MFMA accumulation order -> bit-identical gates.
__global__ __launch_bounds__(128)
__attribute__((amdgpu_waves_per_eu(1, 1)))
void k_mega(const float* __restrict__ x,
    const float* __restrict__ scale, const float* __restrict__ shift,
    const unsigned short* __restrict__ wb0,   // [2,128,512] bf16
    const float* __restrict__ bih0, const float* __restrict__ bhh0,  // [2,128]
    const float* __restrict__ whh0,           // [2,128,32]
    const unsigned short* __restrict__ wlb,   // [3,2,128,64] bf16
    const float* __restrict__ bih, const float* __restrict__ bhh,    // [3,2,128]
    const float* __restrict__ whh,            // [3,2,128,32]
    unsigned short* __restrict__ hout){
  // LDS pool, 17280 dwords = 69120 B:
  //   [0,4352)      rawA  [64][68]
  //   [4352,8576)   glds  [2][32][66]
  //   [8576,17280)  region2: layer0 = xsp [64][136]; layers1-3 = rawB [64][68] + hsp [32][136]
  __shared__ unsigned int smem[17280];
  unsigned int (*rawA)[68]     = (unsigned int (*)[68])smem;
  unsigned int (*glds)[32][66] = (unsigned int (*)[32][66])(smem + 4352);
  unsigned int (*xsp)[136]     = (unsigned int (*)[136])(smem + 8576);
  unsigned int (*rawB)[68]     = (unsigned int (*)[68])(smem + 8576);
  unsigned int (*hsp)[136]     = (unsigned int (*)[136])(smem + 12928);

  int n = blockIdx.x, b = n >> 7, f = n & 127;
  int tid = threadIdx.x;
  int lane = tid & 63, d = tid >> 6;
  int j = lane & 31, hi = lane >> 5;
  int ln = lane & 15, quad = lane >> 4;

  f32x2 w1[16], w2[16];
  float hv = 0.f, c = 0.f;
  unsigned int hgd[4];
  auto step = [&](unsigned int cur, int u){
    float gg1 = __uint_as_float(cur << 16);          // row lane     (i / f)
    float gg2 = __uint_as_float(cur & 0xffff0000u);  // row lane+64  (g / o)
    f32x2 A1 = {gg1, 0.f}, B1 = {0.f, 0.f};
    f32x2 A2 = {gg2, 0.f}, B2 = {0.f, 0.f};
    #pragma unroll
    for (int m = 0; m < 16; m += 2){
      f32x2 h0, h1;
      h0.x = __uint_as_float(__builtin_amdgcn_readlane(__float_as_uint(hv), 2*m));
      h0.y = __uint_as_float(__builtin_amdgcn_readlane(__float_as_uint(hv), 2*m+1));
      h1.x = __uint_as_float(__builtin_amdgcn_readlane(__float_as_uint(hv), 2*m+2));
      h1.y = __uint_as_float(__builtin_amdgcn_readlane(__float_as_uint(hv), 2*m+3));
      A1 += h0*w1[m];   A2 += h0*w2[m];
      B1 += h1*w1[m+1]; B2 += h1*w2[m+1];
    }
    float acc1 = (A1.x + B1.x) + (A1.y + B1.y);
    float acc2 = (A2.x + B2.x) + (A2.y + B2.y);
    float a1 = 1.f/(1.f + __expf(-acc1));            // sigmoid (i or f)
    float x2 = hi ? acc2 : 2.f*acc2;                 // shared-exp: o sigm / g tanh
    float tt = 1.f/(1.f + __expf(-x2));
    float a2 = hi ? tt : 2.f*tt - 1.f;
    ui2 p1 = __builtin_amdgcn_permlane32_swap(__float_as_uint(a1), __float_as_uint(a1), false, false);
    ui2 p2 = __builtin_amdgcn_permlane32_swap(__float_as_uint(a2), __float_as_uint(a2), false, false);
    float i_ = __uint_as_float(p1.x);   // low-half broadcast: i rows
    float f_ = __uint_as_float(p1.y);   // high-half broadcast: f rows
    float g_ = __uint_as_float(p2.x);   // low-half broadcast: g rows
    float o_ = __uint_as_float(p2.y);   // high-half broadcast: o rows
    c = f_*c + i_*g_;
    float tc = 1.f/(1.f + __expf(-2.f*c));
    hv = o_*(2.f*tc - 1.f);
    unsigned int hb = (unsigned int)bfu(hv);
    if ((u & 1) == 0) hgd[u >> 1] = hb;
    else              hgd[u >> 1] |= hb << 16;
  };
  auto loadw = [&](const float* wr1, const float* wr2){
    #pragma unroll
    for (int q = 0; q < 8; ++q){
      float4 aa = *(const float4*)(wr1 + q*4);
      float4 bb = *(const float4*)(wr2 + q*4);
      w1[q*2+0] = (f32x2){aa.x, aa.y}; w1[q*2+1] = (f32x2){aa.z, aa.w};
      w2[q*2+0] = (f32x2){bb.x, bb.y}; w2[q*2+1] = (f32x2){bb.z, bb.w};
    }
    #pragma unroll
    for (int k = 0; k < 16; ++k){             // pin weights (no sink/remat)
      asm volatile("" : "+v"(w1[k]));
      asm volatile("" : "+v"(w2[k]));
    }
  };

  // ---- stage normalized x as packed bf16 (t,t+1) pairs: xsp[c][col], col 0..135
  {
    const float* xr0 = x + (size_t)b*C_*F_*T_ + (size_t)f*T_;
    for (int i = tid; i < 64*34; i += 128){
      int cc = i / 34, q = i - cc*34;
      int t0 = q*4;
      float sc = scale[b*C_+cc], sh = shift[b*C_+cc];
      const float* xr = xr0 + (size_t)cc*F_*T_;
      float u0=0.f,u1=0.f,u2=0.f,u3=0.f,u4=0.f;
      if (t0 < T_){
        float4 v = *(const float4*)(xr + t0);
        u0 = v.x*sc+sh; u1 = v.y*sc+sh; u2 = v.z*sc+sh; u3 = v.w*sc+sh;
        if (t0 + 4 < T_) u4 = xr[t0+4]*sc+sh;
      }
      unsigned int* xc = &xsp[cc][q*4];
      xc[0] = pk2(u0,u1); xc[1] = pk2(u1,u2); xc[2] = pk2(u2,u3); xc[3] = pk2(u3,u4);
    }
  }
  __syncthreads();

  // ---- layer 0: chunked K=512 GEMM (xsp) + chain -> rawA
  {
    loadw(whh0 + (size_t)(d*G_ + lane)*H_, whh0 + (size_t)(d*G_ + lane + 64)*H_);
    float bias[8];
    #pragma unroll
    for (int gt = 0; gt < 8; ++gt)
      bias[gt] = bih0[d*G_ + gt*16 + ln] + bhh0[d*G_ + gt*16 + ln];
    const unsigned short* wpd = wb0 + (size_t)d*G_*CK_;
    unsigned short* hrow = (unsigned short*)&rawA[d*32 + j][0];
    const unsigned int* gr = &glds[d][0][lane];
    hv = 0.f; c = 0.f;

    for (int ch = 0; ch < 4; ++ch){
      int c0 = d ? (89 - 32*ch) : (32*ch);
      #pragma clang loop unroll(disable)
      for (int stl = 0; stl < 2; ++stl){       // register-lean: one 16-step group/pass
        f32x4 acc[8];
        #pragma unroll
        for (int gt = 0; gt < 8; ++gt)
          acc[gt] = (f32x4){bias[gt], bias[gt], bias[gt], bias[gt]};
        int sr = c0 + stl*16 + ln; if (sr < 0) sr = 0;   // junk rows unread
        FragU bcur[8], bnxt[8];
        #pragma unroll
        for (int gt = 0; gt < 8; ++gt)
          bcur[gt].u = *(const uint4*)(wpd + (size_t)(gt*16 + ln)*CK_ + quad*8);
        for (int kb = 0; kb < 16; ++kb){
          if (kb < 15){
            #pragma unroll
            for (int gt = 0; gt < 8; ++gt)
              bnxt[gt].u = *(const uint4*)(wpd + (size_t)(gt*16 + ln)*CK_ + (kb+1)*32 + quad*8);
          }
          FragU a0;
          const unsigned int* rp = &xsp[kb*4 + quad][0];
          a0.u.x = rp[sr]; a0.u.y = rp[sr+2]; a0.u.z = rp[sr+4]; a0.u.w = rp[sr+6];
          #pragma unroll
          for (int gt = 0; gt < 8; ++gt)
            acc[gt] = __builtin_amdgcn_mfma_f32_16x16x32_bf16(a0.s, bcur[gt].s, acc[gt], 0, 0, 0);
          #pragma unroll
          for (int gt = 0; gt < 8; ++gt) bcur[gt] = bnxt[gt];
        }
        #pragma unroll
        for (int gt2 = 0; gt2 < 4; ++gt2)
          #pragma unroll
          for (int r = 0; r < 4; ++r){
            int off = stl*16 + quad*4 + r;
            int ul = d ? (31 - off) : off;   // step-local row (d=1 flipped)
            glds[d][ul][gt2*16 + ln] = pk2(acc[gt2][r], acc[gt2+4][r]);
          }
      }
      asm volatile("" ::: "memory");
      int nfull = (ch < 3) ? 4 : 3;
      for (int gq = 0; gq < nfull; ++gq){
        unsigned int bv[8];
        #pragma unroll
        for (int u = 0; u < 8; ++u) bv[u] = gr[(gq*8 + u)*66];
        #pragma unroll
        for (int u = 0; u < 8; ++u) step(bv[u], u);
        if (!hi) *(uint4*)(hrow + ch*32 + gq*8) = (uint4){hgd[0], hgd[1], hgd[2], hgd[3]};
      }
      if (ch == 3){
        unsigned int bv0 = gr[24*66];
        step(bv0, 0);
        if (!hi) hrow[120] = (unsigned short)(hgd[0] & 0xffffu);
      }
      asm volatile("" ::: "memory");
    }
  }
  __syncthreads();

  // ---- layers 1..3
  unsigned int (*rin)[68]  = rawA;
  unsigned int (*rout)[68] = rawB;
  for (int l = 0; l < 3; ++l){
    // build hsp from rin (both waves cooperate)
    const unsigned short* rawu = (const unsigned short*)&rin[0][0];  // row stride 136 u16
    for (int i = tid; i < 32*128; i += 128){
      int srow = i >> 5, ip = i & 31;
      unsigned int v = 0;
      if (srow <= 120){
        int st = (ip < 16) ? srow : (120 - srow);
        v = (unsigned int)rawu[(2*ip)*136 + st] | ((unsigned int)rawu[(2*ip+1)*136 + st] << 16);
      }
      hsp[ip][srow] = v;
    }
    __syncthreads();

    const unsigned short* wp = wlb + (size_t)((l*2 + d)*G_)*64;
    float bias[8];
    const float* bip = bih + (size_t)(l*2 + d)*G_;
    const float* bhp = bhh + (size_t)(l*2 + d)*G_;
    #pragma unroll
    for (int gt = 0; gt < 8; ++gt) bias[gt] = bip[gt*16 + ln] + bhp[gt*16 + ln];
    loadw(whh + (size_t)((l*2 + d)*G_ + lane)*H_,
          whh + (size_t)((l*2 + d)*G_ + lane + 64)*H_);

    FragU bfrc[8][2];                        // per-layer B-fragments (hoisted)
    #pragma unroll
    for (int gt = 0; gt < 8; ++gt){
      bfrc[gt][0].u = *(const uint4*)(wp + (size_t)(gt*16 + ln)*64 + quad*8);
      bfrc[gt][1].u = *(const uint4*)(wp + (size_t)(gt*16 + ln)*64 + 32 + quad*8);
    }

    unsigned short* hrow = (unsigned short*)&rout[d*32 + j][0];
    const unsigned int* gr = &glds[d][0][lane];
    hv = 0.f; c = 0.f;

    for (int ch = 0; ch < 4; ++ch){
      int c0 = d ? (89 - 32*ch) : (32*ch);   // s-window base this chunk covers
      FragU af[2][2];
      #pragma unroll
      for (int stl = 0; stl < 2; ++stl){
        int srow = c0 + stl*16 + ln; if (srow < 0) srow = 0;   // junk rows unread
        #pragma unroll
        for (int kb = 0; kb < 2; ++kb){
          int ipb = kb*16 + quad*4;
          af[stl][kb].u.x = hsp[ipb+0][srow];
          af[stl][kb].u.y = hsp[ipb+1][srow];
          af[stl][kb].u.z = hsp[ipb+2][srow];
          af[stl][kb].u.w = hsp[ipb+3][srow];
        }
      }
      #pragma unroll
      for (int stl = 0; stl < 2; ++stl)
        #pragma unroll
        for (int gt2 = 0; gt2 < 4; ++gt2){
          f32x4 alo = (f32x4){bias[gt2],   bias[gt2],   bias[gt2],   bias[gt2]};
          f32x4 ahi = (f32x4){bias[gt2+4], bias[gt2+4], bias[gt2+4], bias[gt2+4]};
          alo = __builtin_amdgcn_mfma_f32_16x16x32_bf16(af[stl][0].s, bfrc[gt2  ][0].s, alo, 0, 0, 0);
          alo = __builtin_amdgcn_mfma_f32_16x16x32_bf16(af[stl][1].s, bfrc[gt2  ][1].s, alo, 0, 0, 0);
          ahi = __builtin_amdgcn_mfma_f32_16x16x32_bf16(af[stl][0].s, bfrc[gt2+4][0].s, ahi, 0, 0, 0);
          ahi = __builtin_amdgcn_mfma_f32_16x16x32_bf16(af[stl][1].s, bfrc[gt2+4][1].s, ahi, 0, 0, 0);
          #pragma unroll
          for (int r = 0; r < 4; ++r){
            int off = stl*16 + quad*4 + r;
            int ul = d ? (31 - off) : off;   // step-local row (d=1 flipped)
            glds[d][ul][gt2*16 + ln] = pk2(alo[r], ahi[r]);
          }
        }
      asm volatile("" ::: "memory");         // no ds_read hoists above the writes
      int nfull = (ch < 3) ? 4 : 3;
      for (int gq = 0; gq < nfull; ++gq){
        unsigned int bv[8];
        #pragma unroll
        for (int u = 0; u < 8; ++u) bv[u] = gr[(gq*8 + u)*66];
        #pragma unroll
        for (int u = 0; u < 8; ++u) step(bv[u], u);
        if (!hi) *(uint4*)(hrow + ch*32 + gq*8) = (uint4){hgd[0], hgd[1], hgd[2], hgd[3]};
      }
      if (ch == 3){
        unsigned int bv0 = gr[24*66];
        step(bv0, 0);
        if (!hi) hrow[120] = (unsigned short)(hgd[0] & 0xffffu);
      }
      asm volatile("" ::: "memory");         // next chunk's writes stay below these reads
    }
    __syncthreads();
    unsigned int (*t)[68] = rin; rin = rout; rout = t;
  }

  // ---- final h -> global (layout [n][ci][128] u16, for k_conv)
  unsigned int* ho = (unsigned int*)hout + (size_t)n*64*64;
  for (int i = tid; i < 64*64; i += 128){
    int ci = i >> 6, k = i & 63;
    ho[ci*64 + k] = rin[ci][k];
  }
}

// ---------------------------------------------------------------- ConvTranspose via MFMA + bias + residual
__global__ __launch_bounds__(256) void k_conv(const unsigned short* __restrict__ hin,
    const unsigned short* __restrict__ wA, const float* __restrict__ bct,
    const float* __restrict__ x, float* __restrict__ out){
  __shared__ unsigned int hrawL[64][65];    // raw rows [ci][64 dwords]
  __shared__ unsigned int hp2[64][144];     // overlapping bf16 pairs [ci][col], col=t'+8
  int n = blockIdx.x, b = n >> 7, f = n & 127;
  const unsigned int* hu = (const unsigned int*)hin + (size_t)n*64*64;
  for (int i = threadIdx.x; i < 64*64; i += 256){
    int ci = i >> 6, k = i & 63;
    hrawL[ci][k] = hu[ci*64 + k];
  }
  __syncthreads();
  const unsigned short* rawu = (const unsigned short*)&hrawL[0][0];  // row stride 130 u16
  for (int it = threadIdx.x; it < 64*136; it += 256){
    int ci = it / 136, col = it - ci*136;
    int t0 = col - 8;
    int i0 = (ci < 32) ? t0 : (120 - t0);
    int i1 = (ci < 32) ? (t0+1) : (119 - t0);
    unsigned int lo  = (t0   >= 0 && t0   <= 120) ? rawu[ci*130 + i0] : 0u;
    unsigned int hi2 = (t0+1 >= 0 && t0+1 <= 120) ? rawu[ci*130 + i1] : 0u;
    hp2[ci][col] = lo | (hi2 << 16);
  }
  __syncthreads();
  int lane = threadIdx.x & 63, wv = threadIdx.x >> 6;
  int ln = lane & 15, quad = lane >> 4;
  const unsigned short* wp = wA + (size_t)(wv*16 + ln)*512;
  f32x4 acc[8];
  #pragma unroll
  for (int nt = 0; nt < 8; ++nt) acc[nt] = (f32x4){0.f,0.f,0.f,0.f};
  for (int kb = 0; kb < 16; ++kb){
    FragU afr; afr.u = *(const uint4*)(wp + kb*32 + quad*8);
    int ci = kb*4 + quad;
    #pragma unroll
    for (int nt = 0; nt < 8; ++nt){
      FragU bfr;
      const unsigned int* rp = &hp2[ci][nt*16 + ln + 1];
      bfr.u.x = rp[0]; bfr.u.y = rp[2]; bfr.u.z = rp[4]; bfr.u.w = rp[6];
      acc[nt] = __builtin_amdgcn_mfma_f32_16x16x32_bf16(afr.s, bfr.s, acc[nt], 0, 0, 0);
    }
  }
  float bb[4];
  #pragma unroll
  for (int r = 0; r < 4; ++r) bb[r] = bct[wv*16 + quad*4 + r];
  #pragma unroll
  for (int nt = 0; nt < 8; ++nt)
    #pragma unroll
    for (int r = 0; r < 4; ++r){
      int co = wv*16 + quad*4 + r, t = nt*16 + ln;
      size_t idx = ((size_t)(b*64 + co)*128 + f)*128 + t;
      out[idx] = acc[nt][r] + bb[r] + x[idx];
    }
}

// ----------------------------------------------------------------
extern "C" void kernel_launch(void* const* d_in, const int* in_sizes, int n_in,
                              void* d_out, int out_size, void* d_ws, size_t ws_size,
                              hipStream_t stream){
  const float* x     = (const float*)d_in[0];
  const float* gamma = (const float*)d_in[1];
  const float* beta  = (const float*)d_in[2];
  const float* wih0  = (const float*)d_in[3];   // [2,128,512]
  const float* whh0  = (const float*)d_in[4];   // [2,128,32]
  const float* bih0  = (const float*)d_in[5];
  const float* bhh0  = (const float*)d_in[6];
  const float* wih   = (const float*)d_in[7];   // [3,2,128,64]
  const float* whh   = (const float*)d_in[8];   // [3,2,128,32]
  const float* bih   = (const float*)d_in[9];
  const float* bhh   = (const float*)d_in[10];
  const float* wct   = (const float*)d_in[11];  // [64,64,8]
  const float* bct   = (const float*)d_in[12];
  float* out = (float*)d_out;

  char* wsb = (char*)d_ws;
  float*          scale = (float*)(wsb);                       // 1 KB
  float*          shift = (float*)(wsb + 1024);                // 1 KB
  unsigned short* hA    = (unsigned short*)(wsb + 31721472);   // 8,388,608 B (final h)
  unsigned short* wb0   = (unsigned short*)(wsb + 48498688);   // 262,144 B
  unsigned short* wlb   = (unsigned short*)(wsb + 48760832);   // 98,304 B
  unsigned short* wcv   = (unsigned short*)(wsb + 48859136);   // 65,536 B

  k_norm<<<256, 256, 0, stream>>>(x, gamma, beta, scale, shift);
  k_wcvt<<<512, 256, 0, stream>>>(wih0, wb0, 2*G_*CK_);
  k_wcvt<<<192, 256, 0, stream>>>(wih,  wlb, 3*2*G_*64);
  k_wrev<<<128, 256, 0, stream>>>(wct,  wcv, 64*512);
  k_mega<<<512, 128, 0, stream>>>(x, scale, shift, wb0, bih0, bhh0, whh0,
                                  wlb, bih, bhh, whh, hA);
  k_conv<<<512, 256, 0, stream>>>(hA, wcv, bct, x, out);
}

// Round 8
// 334.845 us; speedup vs baseline: 1.2200x; 1.2200x over previous
//
#include <hip/hip_runtime.h>

#define B_ 4
#define C_ 64
#define F_ 128
#define T_ 128
#define K_ 8
#define H_ 32
#define S_ 121   // T - K + 1
#define N_ 512   // B * F
#define G_ 128   // 4 * H
#define CK_ 512  // C * K

typedef __attribute__((ext_vector_type(8))) short short8;
typedef __attribute__((ext_vector_type(4))) float f32x4;
typedef __attribute__((ext_vector_type(2))) float f32x2;
typedef __attribute__((ext_vector_type(2))) unsigned int ui2;
union FragU { uint4 u; short8 s; };

__device__ __forceinline__ unsigned int pk2(float a, float b){   // RNE f32->bf16 pair
  unsigned int ua = __float_as_uint(a); ua += 0x7fffu + ((ua>>16)&1u);
  unsigned int ub = __float_as_uint(b); ub += 0x7fffu + ((ub>>16)&1u);
  return (ua>>16) | (ub & 0xffff0000u);
}
__device__ __forceinline__ unsigned short bfu(float a){          // RNE f32->bf16
  unsigned int ua = __float_as_uint(a); ua += 0x7fffu + ((ua>>16)&1u);
  return (unsigned short)(ua>>16);
}

// gx gate-pair interleaved slot: lane l of the chain reads one dword = (row l | row l+64 <<16)
__device__ __forceinline__ int gslot(int g){ return ((g & 63) << 1) | (g >> 6); }

// ---------------------------------------------------------------- instance norm stats
__global__ __launch_bounds__(256) void k_norm(const float* __restrict__ x,
    const float* __restrict__ gamma, const float* __restrict__ beta,
    float* __restrict__ scale, float* __restrict__ shift){
  int bc = blockIdx.x;
  const float* p = x + (size_t)bc * (F_*T_);
  float s = 0.f, q = 0.f;
  for (int i = threadIdx.x; i < F_*T_; i += 256){ float v = p[i]; s += v; q += v*v; }
  #pragma unroll
  for (int o = 32; o; o >>= 1){ s += __shfl_down(s, o); q += __shfl_down(q, o); }
  __shared__ float ss[4], qq[4];
  int w = threadIdx.x >> 6;
  if ((threadIdx.x & 63) == 0){ ss[w] = s; qq[w] = q; }
  __syncthreads();
  if (threadIdx.x == 0){
    s = ss[0]+ss[1]+ss[2]+ss[3]; q = qq[0]+qq[1]+qq[2]+qq[3];
    float mu  = s / (float)(F_*T_);
    float var = q / (float)(F_*T_) - mu*mu;
    if (var < 0.f) var = 0.f;
    int c = bc & (C_-1);
    float sc = gamma[c] * rsqrtf(var + 1e-5f);
    scale[bc] = sc;
    shift[bc] = beta[c] - mu * sc;
  }
}

// ---------------------------------------------------------------- weight f32 -> bf16
__global__ __launch_bounds__(256) void k_wcvt(const float* __restrict__ a,
    unsigned short* __restrict__ o, int nel){
  int i = blockIdx.x*256 + threadIdx.x;
  if (i < nel) o[i] = bfu(a[i]);
}
// conv weights: bf16 + reverse k within each 8-block (absorbs conv flip into GEMM)
__global__ __launch_bounds__(256) void k_wrev(const float* __restrict__ a,
    unsigned short* __restrict__ o, int nel){
  int i = blockIdx.x*256 + threadIdx.x;
  if (i < nel){ int j = (i & ~7) | (7 - (i & 7)); o[i] = bfu(a[j]); }
}

// ---------------------------------------------------------------- layer-0 projection, MFMA bf16
// (round-4 verified version, restored: multi-wave TLP belongs here, not in k_mega)
__global__ __launch_bounds__(256) void k_gx0(const float* __restrict__ x,
    const float* __restrict__ scale, const float* __restrict__ shift,
    const unsigned short* __restrict__ wb0, const float* __restrict__ bi,
    const float* __restrict__ bh, unsigned short* __restrict__ gx){
  __shared__ unsigned int xsp[C_][80];      // packed bf16 pairs (t, t+1), local cols [0,72)
  int n = blockIdx.x >> 1, half = blockIdx.x & 1;
  int b = n >> 7, f = n & 127;
  const float* xb = x + (size_t)b*C_*F_*T_ + (size_t)f*T_;
  for (int i = threadIdx.x; i < C_*18; i += 256){
    int c = i / 18, q = i - c*18;
    int t0 = half*64 + q*4;
    float sc = scale[b*C_+c], sh = shift[b*C_+c];
    const float* xr = xb + (size_t)c*F_*T_;
    float4 v = (float4){0.f,0.f,0.f,0.f};
    float e = 0.f;
    bool in4 = (t0 < T_);
    if (in4) v = *(const float4*)(xr + t0);
    if (t0 + 4 < T_) e = xr[t0 + 4];
    float u0 = in4 ? v.x*sc+sh : 0.f;
    float u1 = in4 ? v.y*sc+sh : 0.f;
    float u2 = in4 ? v.z*sc+sh : 0.f;
    float u3 = in4 ? v.w*sc+sh : 0.f;
    float u4 = (t0+4 < T_) ? e*sc+sh : 0.f;
    unsigned int* xc = &xsp[c][q*4];
    xc[0] = pk2(u0,u1); xc[1] = pk2(u1,u2); xc[2] = pk2(u2,u3); xc[3] = pk2(u3,u4);
  }
  __syncthreads();
  int lane = threadIdx.x & 63, wv = threadIdx.x >> 6;
  int ln = lane & 15, quad = lane >> 4;
  int g256[4]; f32x4 acc[4][4];
  #pragma unroll
  for (int gi = 0; gi < 4; ++gi){
    g256[gi] = (wv*4 + gi)*16 + ln;
    float bv = bi[g256[gi]] + bh[g256[gi]];
    #pragma unroll
    for (int stl = 0; stl < 4; ++stl) acc[stl][gi] = (f32x4){bv, bv, bv, bv};
  }
  FragU bcur[4], bnxt[4];
  #pragma unroll
  for (int gi = 0; gi < 4; ++gi)
    bcur[gi].u = *(const uint4*)(wb0 + (size_t)g256[gi]*CK_ + quad*8);
  for (int kb = 0; kb < 16; ++kb){
    if (kb < 15){
      #pragma unroll
      for (int gi = 0; gi < 4; ++gi)
        bnxt[gi].u = *(const uint4*)(wb0 + (size_t)g256[gi]*CK_ + (kb+1)*32 + quad*8);
    }
    #pragma unroll
    for (int stl = 0; stl < 4; ++stl){
      FragU a;
      const unsigned int* rp = &xsp[kb*4 + quad][stl*16 + ln];
      a.u.x = rp[0]; a.u.y = rp[2]; a.u.z = rp[4]; a.u.w = rp[6];
      #pragma unroll
      for (int gi = 0; gi < 4; ++gi)
        acc[stl][gi] = __builtin_amdgcn_mfma_f32_16x16x32_bf16(a.s, bcur[gi].s, acc[stl][gi], 0, 0, 0);
    }
    #pragma unroll
    for (int gi = 0; gi < 4; ++gi) bcur[gi] = bnxt[gi];
  }
  #pragma unroll
  for (int stl = 0; stl < 4; ++stl)
    #pragma unroll
    for (int gi = 0; gi < 4; ++gi){
      int d = g256[gi] >> 7, g = g256[gi] & 127;
      #pragma unroll
      for (int r = 0; r < 4; ++r){
        int s = (half*4 + stl)*16 + quad*4 + r;
        if (s < S_)
          gx[((size_t)(d*N_ + n)*S_ + s)*G_ + gslot(g)] = bfu(acc[stl][gi][r]);
      }
    }
}

// ---------------------------------------------------------------- fused LSTM stack + conv tail
// Round-13: revert to round-4 chain structure (k_gx0 restored; layer-0 GEMM
// un-fused per round-7 lesson: bulk GEMM needs TLP, the 1-wave/SIMD kernel must
// hold only serial-dependent work). NEW: k_conv fused as a tail -- block n's
// final h is already in LDS (rin=rawB); conv GEMM is only 16 kb iters of
// cache-hot loads. Eliminates hA write+read (16MB) and the k_conv dispatch.
// hp2 staged in two 32-ci passes so it fits the freed rawA region exactly.
__global__ __launch_bounds__(128)
__attribute__((amdgpu_waves_per_eu(1, 1)))
void k_mega(const unsigned short* __restrict__ gx,
    const float* __restrict__ whh0,           // [2,128,32]
    const unsigned short* __restrict__ wlb,   // [3,2,128,64] bf16
    const float* __restrict__ bih, const float* __restrict__ bhh,  // [3,2,128]
    const float* __restrict__ whh,            // [3,2,128,32]
    const unsigned short* __restrict__ wcv,   // [64,512] bf16, k-reversed
    const float* __restrict__ bct,
    const float* __restrict__ x,
    float* __restrict__ out){
  // LDS pool, 17280 dwords = 69120 B:
  //   rawA [0,4352)  rawB [4352,8704)  glds [8704,12928)  hsp [12928,17280)
  //   conv tail: hp2h [32][136] overlays rawA (final rin = rawB)
  __shared__ unsigned int smem[17280];
  unsigned int (*rawA)[68]     = (unsigned int (*)[68])smem;
  unsigned int (*rawB)[68]     = (unsigned int (*)[68])(smem + 4352);
  unsigned int (*glds)[32][66] = (unsigned int (*)[32][66])(smem + 8704);
  unsigned int (*hsp)[136]     = (unsigned int (*)[136])(smem + 12928);
  unsigned int (*hp2h)[136]    = (unsigned int (*)[136])smem;

  int n = blockIdx.x, b = n >> 7, f = n & 127;
  int tid = threadIdx.x;
  int lane = tid & 63, d = tid >> 6;
  int j = lane & 31, hi = lane >> 5;
  int ln = lane & 15, quad = lane >> 4;

  f32x2 w1[16], w2[16];
  float hv = 0.f, c = 0.f;
  unsigned int hgd[4];
  auto step = [&](unsigned int cur, int u){
    float gg1 = __uint_as_float(cur << 16);          // row lane     (i / f)
    float gg2 = __uint_as_float(cur & 0xffff0000u);  // row lane+64  (g / o)
    f32x2 A1 = {gg1, 0.f}, B1 = {0.f, 0.f};
    f32x2 A2 = {gg2, 0.f}, B2 = {0.f, 0.f};
    #pragma unroll
    for (int m = 0; m < 16; m += 2){
      f32x2 h0, h1;
      h0.x = __uint_as_float(__builtin_amdgcn_readlane(__float_as_uint(hv), 2*m));
      h0.y = __uint_as_float(__builtin_amdgcn_readlane(__float_as_uint(hv), 2*m+1));
      h1.x = __uint_as_float(__builtin_amdgcn_readlane(__float_as_uint(hv), 2*m+2));
      h1.y = __uint_as_float(__builtin_amdgcn_readlane(__float_as_uint(hv), 2*m+3));
      A1 += h0*w1[m];   A2 += h0*w2[m];
      B1 += h1*w1[m+1]; B2 += h1*w2[m+1];
    }
    float acc1 = (A1.x + B1.x) + (A1.y + B1.y);
    float acc2 = (A2.x + B2.x) + (A2.y + B2.y);
    float a1 = 1.f/(1.f + __expf(-acc1));            // sigmoid (i or f)
    float x2 = hi ? acc2 : 2.f*acc2;                 // shared-exp: o sigm / g tanh
    float tt = 1.f/(1.f + __expf(-x2));
    float a2 = hi ? tt : 2.f*tt - 1.f;
    ui2 p1 = __builtin_amdgcn_permlane32_swap(__float_as_uint(a1), __float_as_uint(a1), false, false);
    ui2 p2 = __builtin_amdgcn_permlane32_swap(__float_as_uint(a2), __float_as_uint(a2), false, false);
    float i_ = __uint_as_float(p1.x);   // low-half broadcast: i rows
    float f_ = __uint_as_float(p1.y);   // high-half broadcast: f rows
    float g_ = __uint_as_float(p2.x);   // low-half broadcast: g rows
    float o_ = __uint_as_float(p2.y);   // high-half broadcast: o rows
    c = f_*c + i_*g_;
    float tc = 1.f/(1.f + __expf(-2.f*c));
    hv = o_*(2.f*tc - 1.f);
    unsigned int hb = (unsigned int)bfu(hv);
    if ((u & 1) == 0) hgd[u >> 1] = hb;
    else              hgd[u >> 1] |= hb << 16;
  };
  auto loadw = [&](const float* wr1, const float* wr2){
    #pragma unroll
    for (int q = 0; q < 8; ++q){
      float4 aa = *(const float4*)(wr1 + q*4);
      float4 bb = *(const float4*)(wr2 + q*4);
      w1[q*2+0] = (f32x2){aa.x, aa.y}; w1[q*2+1] = (f32x2){aa.z, aa.w};
      w2[q*2+0] = (f32x2){bb.x, bb.y}; w2[q*2+1] = (f32x2){bb.z, bb.w};
    }
    #pragma unroll
    for (int k = 0; k < 16; ++k){             // pin weights (no sink/remat)
      asm volatile("" : "+v"(w1[k]));
      asm volatile("" : "+v"(w2[k]));
    }
  };

  // ---- layer 0 chain: gx (global) -> rawA
  {
    loadw(whh0 + (size_t)(d*G_ + lane)*H_, whh0 + (size_t)(d*G_ + lane + 64)*H_);
    const unsigned int* gxu = (const unsigned int*)gx;
    ptrdiff_t stride = d ? -64 : 64;
    const unsigned int* p0 = gxu + ((size_t)(d*N_ + n)*S_ + (d ? (S_-1) : 0))*64 + lane;
    unsigned short* hrow = (unsigned short*)&rawA[d*32 + j][0];
    unsigned int bufA[8], bufB[8];
    #pragma unroll
    for (int u = 0; u < 8; ++u) bufA[u] = p0[stride*u];
    for (int gg = 0; gg < 7; ++gg){
      int g0 = gg*2;
      #pragma unroll
      for (int u = 0; u < 8; ++u) bufB[u] = p0[stride*(8*(g0+1) + u)];
      #pragma unroll
      for (int u = 0; u < 8; ++u) step(bufA[u], u);
      if (!hi) *(uint4*)(hrow + 8*g0) = (uint4){hgd[0], hgd[1], hgd[2], hgd[3]};
      #pragma unroll
      for (int u = 0; u < 8; ++u) bufA[u] = p0[stride*(8*(g0+2) + u)];
      #pragma unroll
      for (int u = 0; u < 8; ++u) step(bufB[u], u);
      if (!hi) *(uint4*)(hrow + 8*(g0+1)) = (uint4){hgd[0], hgd[1], hgd[2], hgd[3]};
    }
    bufB[0] = p0[stride*120];
    #pragma unroll
    for (int u = 0; u < 8; ++u) step(bufA[u], u);
    if (!hi) *(uint4*)(hrow + 112) = (uint4){hgd[0], hgd[1], hgd[2], hgd[3]};
    step(bufB[0], 0);
    if (!hi) hrow[120] = (unsigned short)(hgd[0] & 0xffffu);
  }
  __syncthreads();

  // ---- layers 1..3
  unsigned int (*rin)[68]  = rawA;
  unsigned int (*rout)[68] = rawB;
  for (int l = 0; l < 3; ++l){
    // build hsp from rin (both waves cooperate)
    const unsigned short* rawu = (const unsigned short*)&rin[0][0];  // row stride 136 u16
    for (int i = tid; i < 32*128; i += 128){
      int srow = i >> 5, ip = i & 31;
      unsigned int v = 0;
      if (srow <= 120){
        int st = (ip < 16) ? srow : (120 - srow);
        v = (unsigned int)rawu[(2*ip)*136 + st] | ((unsigned int)rawu[(2*ip+1)*136 + st] << 16);
      }
      hsp[ip][srow] = v;
    }
    __syncthreads();

    const unsigned short* wp = wlb + (size_t)((l*2 + d)*G_)*64;
    float bias[8];
    const float* bip = bih + (size_t)(l*2 + d)*G_;
    const float* bhp = bhh + (size_t)(l*2 + d)*G_;
    #pragma unroll
    for (int gt = 0; gt < 8; ++gt) bias[gt] = bip[gt*16 + ln] + bhp[gt*16 + ln];
    loadw(whh + (size_t)((l*2 + d)*G_ + lane)*H_,
          whh + (size_t)((l*2 + d)*G_ + lane + 64)*H_);

    FragU bfrc[8][2];                        // per-layer B-fragments (hoisted)
    #pragma unroll
    for (int gt = 0; gt < 8; ++gt){
      bfrc[gt][0].u = *(const uint4*)(wp + (size_t)(gt*16 + ln)*64 + quad*8);
      bfrc[gt][1].u = *(const uint4*)(wp + (size_t)(gt*16 + ln)*64 + 32 + quad*8);
    }

    unsigned short* hrow = (unsigned short*)&rout[d*32 + j][0];
    const unsigned int* gr = &glds[d][0][lane];
    hv = 0.f; c = 0.f;

    for (int ch = 0; ch < 4; ++ch){
      int c0 = d ? (89 - 32*ch) : (32*ch);   // s-window base this chunk covers
      FragU af[2][2];
      #pragma unroll
      for (int stl = 0; stl < 2; ++stl){
        int srow = c0 + stl*16 + ln; if (srow < 0) srow = 0;   // junk rows unread
        #pragma unroll
        for (int kb = 0; kb < 2; ++kb){
          int ipb = kb*16 + quad*4;
          af[stl][kb].u.x = hsp[ipb+0][srow];
          af[stl][kb].u.y = hsp[ipb+1][srow];
          af[stl][kb].u.z = hsp[ipb+2][srow];
          af[stl][kb].u.w = hsp[ipb+3][srow];
        }
      }
      #pragma unroll
      for (int stl = 0; stl < 2; ++stl)
        #pragma unroll
        for (int gt2 = 0; gt2 < 4; ++gt2){
          f32x4 alo = (f32x4){bias[gt2],   bias[gt2],   bias[gt2],   bias[gt2]};
          f32x4 ahi = (f32x4){bias[gt2+4], bias[gt2+4], bias[gt2+4], bias[gt2+4]};
          alo = __builtin_amdgcn_mfma_f32_16x16x32_bf16(af[stl][0].s, bfrc[gt2  ][0].s, alo, 0, 0, 0);
          alo = __builtin_amdgcn_mfma_f32_16x16x32_bf16(af[stl][1].s, bfrc[gt2  ][1].s, alo, 0, 0, 0);
          ahi = __builtin_amdgcn_mfma_f32_16x16x32_bf16(af[stl][0].s, bfrc[gt2+4][0].s, ahi, 0, 0, 0);
          ahi = __builtin_amdgcn_mfma_f32_16x16x32_bf16(af[stl][1].s, bfrc[gt2+4][1].s, ahi, 0, 0, 0);
          #pragma unroll
          for (int r = 0; r < 4; ++r){
            int off = stl*16 + quad*4 + r;
            int ul = d ? (31 - off) : off;   // step-local row (d=1 flipped)
            glds[d][ul][gt2*16 + ln] = pk2(alo[r], ahi[r]);
          }
        }
      asm volatile("" ::: "memory");         // no ds_read hoists above the writes
      int nfull = (ch < 3) ? 4 : 3;
      for (int gq = 0; gq < nfull; ++gq){
        unsigned int bv[8];
        #pragma unroll
        for (int u = 0; u < 8; ++u) bv[u] = gr[(gq*8 + u)*66];
        #pragma unroll
        for (int u = 0; u < 8; ++u) step(bv[u], u);
        if (!hi) *(uint4*)(hrow + ch*32 + gq*8) = (uint4){hgd[0], hgd[1], hgd[2], hgd[3]};
      }
      if (ch == 3){
        unsigned int bv0 = gr[24*66];
        step(bv0, 0);
        if (!hi) hrow[120] = (unsigned short)(hgd[0] & 0xffffu);
      }
      asm volatile("" ::: "memory");         // next chunk's writes stay below these reads
    }
    __syncthreads();
    unsigned int (*t)[68] = rin; rin = rout; rout = t;
  }
  // final rin = rawB; rawA/glds/hsp now dead

  // ---- conv-transpose tail (was k_conv): rin -> out, two 32-ci passes
  {
    f32x4 ac[2][8];
    #pragma unroll
    for (int cg = 0; cg < 2; ++cg)
      #pragma unroll
      for (int nt = 0; nt < 8; ++nt) ac[cg][nt] = (f32x4){0.f,0.f,0.f,0.f};
    const unsigned short* wp0 = wcv + (size_t)(d*32 + ln)*512;
    const unsigned short* wp1 = wcv + (size_t)(d*32 + 16 + ln)*512;
    const unsigned short* rawu2 = (const unsigned short*)&rin[0][0];  // stride 136 u16
    for (int pass = 0; pass < 2; ++pass){
      // build hp2h for ci in [pass*32, pass*32+32)
      for (int it = tid; it < 32*136; it += 128){
        int cil = it / 136, col = it - cil*136;
        int ci = pass*32 + cil;
        int t0 = col - 8;
        int i0 = (ci < 32) ? t0 : (120 - t0);
        int i1 = (ci < 32) ? (t0+1) : (119 - t0);
        unsigned int lo  = (t0   >= 0 && t0   <= 120) ? rawu2[ci*136 + i0] : 0u;
        unsigned int hi2 = (t0+1 >= 0 && t0+1 <= 120) ? rawu2[ci*136 + i1] : 0u;
        hp2h[cil][col] = lo | (hi2 << 16);
      }
      __syncthreads();
      for (int kb = pass*8; kb < pass*8 + 8; ++kb){
        FragU a0, a1;
        a0.u = *(const uint4*)(wp0 + kb*32 + quad*8);
        a1.u = *(const uint4*)(wp1 + kb*32 + quad*8);
        int cil = (kb - pass*8)*4 + quad;
        #pragma unroll
        for (int nt = 0; nt < 8; ++nt){
          FragU bfr;
          const unsigned int* rp = &hp2h[cil][nt*16 + ln + 1];
          bfr.u.x = rp[0]; bfr.u.y = rp[2]; bfr.u.z = rp[4]; bfr.u.w = rp[6];
          ac[0][nt] = __builtin_amdgcn_mfma_f32_16x16x32_bf16(a0.s, bfr.s, ac[0][nt], 0, 0, 0);
          ac[1][nt] = __builtin_amdgcn_mfma_f32_16x16x32_bf16(a1.s, bfr.s, ac[1][nt], 0, 0, 0);
        }
      }
      __syncthreads();   // pass-0 reads complete before pass-1 overwrites hp2h
    }
    #pragma unroll
    for (int cg = 0; cg < 2; ++cg){
      float bb[4];
      #pragma unroll
      for (int r = 0; r < 4; ++r) bb[r] = bct[d*32 + cg*16 + quad*4 + r];
      #pragma unroll
      for (int nt = 0; nt < 8; ++nt)
        #pragma unroll
        for (int r = 0; r < 4; ++r){
          int co = d*32 + cg*16 + quad*4 + r, t = nt*16 + ln;
          size_t idx = ((size_t)(b*64 + co)*128 + f)*128 + t;
          out[idx] = ac[cg][nt][r] + bb[r] + x[idx];
        }
    }
  }
}

// ----------------------------------------------------------------
extern "C" void kernel_launch(void* const* d_in, const int* in_sizes, int n_in,
                              void* d_out, int out_size, void* d_ws, size_t ws_size,
                              hipStream_t stream){
  const float* x     = (const float*)d_in[0];
  const float* gamma = (const float*)d_in[1];
  const float* beta  = (const float*)d_in[2];
  const float* wih0  = (const float*)d_in[3];   // [2,128,512]
  const float* whh0  = (const float*)d_in[4];   // [2,128,32]
  const float* bih0  = (const float*)d_in[5];
  const float* bhh0  = (const float*)d_in[6];
  const float* wih   = (const float*)d_in[7];   // [3,2,128,64]
  const float* whh   = (const float*)d_in[8];   // [3,2,128,32]
  const float* bih   = (const float*)d_in[9];
  const float* bhh   = (const float*)d_in[10];
  const float* wct   = (const float*)d_in[11];  // [64,64,8]
  const float* bct   = (const float*)d_in[12];
  float* out = (float*)d_out;

  char* wsb = (char*)d_ws;
  float*          scale = (float*)(wsb);                       // 1 KB
  float*          shift = (float*)(wsb + 1024);                // 1 KB
  unsigned short* gx    = (unsigned short*)(wsb + 2048);       // 31,719,424 B (layer-0 gates)
  unsigned short* wb0   = (unsigned short*)(wsb + 48498688);   // 262,144 B
  unsigned short* wlb   = (unsigned short*)(wsb + 48760832);   // 98,304 B
  unsigned short* wcv   = (unsigned short*)(wsb + 48859136);   // 65,536 B

  k_norm<<<256, 256, 0, stream>>>(x, gamma, beta, scale, shift);
  k_wcvt<<<512, 256, 0, stream>>>(wih0, wb0, 2*G_*CK_);
  k_wcvt<<<192, 256, 0, stream>>>(wih,  wlb, 3*2*G_*64);
  k_wrev<<<128, 256, 0, stream>>>(wct,  wcv, 64*512);
  k_gx0 <<<1024, 256, 0, stream>>>(x, scale, shift, wb0, bih0, bhh0, gx);
  k_mega<<<512, 128, 0, stream>>>(gx, whh0, wlb, bih, bhh, whh, wcv, bct, x, out);
}

// Round 9
// 331.083 us; speedup vs baseline: 1.2338x; 1.0114x over previous
//
#include <hip/hip_runtime.h>

#define B_ 4
#define C_ 64
#define F_ 128
#define T_ 128
#define K_ 8
#define H_ 32
#define S_ 121   // T - K + 1
#define N_ 512   // B * F
#define G_ 128   // 4 * H
#define CK_ 512  // C * K

typedef __attribute__((ext_vector_type(8))) short short8;
typedef __attribute__((ext_vector_type(4))) float f32x4;
typedef __attribute__((ext_vector_type(2))) float f32x2;
typedef __attribute__((ext_vector_type(2))) unsigned int ui2;
union FragU { uint4 u; short8 s; };

__device__ __forceinline__ unsigned int pk2(float a, float b){   // RNE f32->bf16 pair
  unsigned int ua = __float_as_uint(a); ua += 0x7fffu + ((ua>>16)&1u);
  unsigned int ub = __float_as_uint(b); ub += 0x7fffu + ((ub>>16)&1u);
  return (ua>>16) | (ub & 0xffff0000u);
}
__device__ __forceinline__ unsigned short bfu(float a){          // RNE f32->bf16
  unsigned int ua = __float_as_uint(a); ua += 0x7fffu + ((ua>>16)&1u);
  return (unsigned short)(ua>>16);
}

// gx gate-pair interleaved slot: lane l of the chain reads one dword = (row l | row l+64 <<16)
__device__ __forceinline__ int gslot(int g){ return ((g & 63) << 1) | (g >> 6); }

// ---------------------------------------------------------------- instance norm stats
__global__ __launch_bounds__(256) void k_norm(const float* __restrict__ x,
    const float* __restrict__ gamma, const float* __restrict__ beta,
    float* __restrict__ scale, float* __restrict__ shift){
  int bc = blockIdx.x;
  const float* p = x + (size_t)bc * (F_*T_);
  float s = 0.f, q = 0.f;
  for (int i = threadIdx.x; i < F_*T_; i += 256){ float v = p[i]; s += v; q += v*v; }
  #pragma unroll
  for (int o = 32; o; o >>= 1){ s += __shfl_down(s, o); q += __shfl_down(q, o); }
  __shared__ float ss[4], qq[4];
  int w = threadIdx.x >> 6;
  if ((threadIdx.x & 63) == 0){ ss[w] = s; qq[w] = q; }
  __syncthreads();
  if (threadIdx.x == 0){
    s = ss[0]+ss[1]+ss[2]+ss[3]; q = qq[0]+qq[1]+qq[2]+qq[3];
    float mu  = s / (float)(F_*T_);
    float var = q / (float)(F_*T_) - mu*mu;
    if (var < 0.f) var = 0.f;
    int c = bc & (C_-1);
    float sc = gamma[c] * rsqrtf(var + 1e-5f);
    scale[bc] = sc;
    shift[bc] = beta[c] - mu * sc;
  }
}

// ---------------------------------------------------------------- weight f32 -> bf16
__global__ __launch_bounds__(256) void k_wcvt(const float* __restrict__ a,
    unsigned short* __restrict__ o, int nel){
  int i = blockIdx.x*256 + threadIdx.x;
  if (i < nel) o[i] = bfu(a[i]);
}
// conv weights: bf16 + reverse k within each 8-block (absorbs conv flip into GEMM)
__global__ __launch_bounds__(256) void k_wrev(const float* __restrict__ a,
    unsigned short* __restrict__ o, int nel){
  int i = blockIdx.x*256 + threadIdx.x;
  if (i < nel){ int j = (i & ~7) | (7 - (i & 7)); o[i] = bfu(a[j]); }
}

// ---------------------------------------------------------------- layer-0 projection, MFMA bf16
// Round-14: epilogue was 64 scattered 2B global stores/thread (write-path
// saturation: VALU 13%, MFMA 11%, HBM 9% all idle). Now: stage gates in LDS in
// gslot u16 layout (two d-passes sharing one buffer), then coalesced uint4
// stores -- 8 x 16B/thread. Identical bytes to identical addresses.
__global__ __launch_bounds__(256) void k_gx0(const float* __restrict__ x,
    const float* __restrict__ scale, const float* __restrict__ shift,
    const unsigned short* __restrict__ wb0, const float* __restrict__ bi,
    const float* __restrict__ bh, unsigned short* __restrict__ gx){
  __shared__ unsigned int xsp[C_][80];      // packed bf16 pairs (t, t+1), local cols [0,72)
  __shared__ unsigned int glb[64][68];      // gate staging: [srow][128 u16 + pad], stride 136 u16
  int n = blockIdx.x >> 1, half = blockIdx.x & 1;
  int b = n >> 7, f = n & 127;
  const float* xb = x + (size_t)b*C_*F_*T_ + (size_t)f*T_;
  for (int i = threadIdx.x; i < C_*18; i += 256){
    int c = i / 18, q = i - c*18;
    int t0 = half*64 + q*4;
    float sc = scale[b*C_+c], sh = shift[b*C_+c];
    const float* xr = xb + (size_t)c*F_*T_;
    float4 v = (float4){0.f,0.f,0.f,0.f};
    float e = 0.f;
    bool in4 = (t0 < T_);
    if (in4) v = *(const float4*)(xr + t0);
    if (t0 + 4 < T_) e = xr[t0 + 4];
    float u0 = in4 ? v.x*sc+sh : 0.f;
    float u1 = in4 ? v.y*sc+sh : 0.f;
    float u2 = in4 ? v.z*sc+sh : 0.f;
    float u3 = in4 ? v.w*sc+sh : 0.f;
    float u4 = (t0+4 < T_) ? e*sc+sh : 0.f;
    unsigned int* xc = &xsp[c][q*4];
    xc[0] = pk2(u0,u1); xc[1] = pk2(u1,u2); xc[2] = pk2(u2,u3); xc[3] = pk2(u3,u4);
  }
  __syncthreads();
  int lane = threadIdx.x & 63, wv = threadIdx.x >> 6;
  int ln = lane & 15, quad = lane >> 4;
  int g256[4]; f32x4 acc[4][4];
  #pragma unroll
  for (int gi = 0; gi < 4; ++gi){
    g256[gi] = (wv*4 + gi)*16 + ln;
    float bv = bi[g256[gi]] + bh[g256[gi]];
    #pragma unroll
    for (int stl = 0; stl < 4; ++stl) acc[stl][gi] = (f32x4){bv, bv, bv, bv};
  }
  FragU bcur[4], bnxt[4];
  #pragma unroll
  for (int gi = 0; gi < 4; ++gi)
    bcur[gi].u = *(const uint4*)(wb0 + (size_t)g256[gi]*CK_ + quad*8);
  for (int kb = 0; kb < 16; ++kb){
    if (kb < 15){
      #pragma unroll
      for (int gi = 0; gi < 4; ++gi)
        bnxt[gi].u = *(const uint4*)(wb0 + (size_t)g256[gi]*CK_ + (kb+1)*32 + quad*8);
    }
    #pragma unroll
    for (int stl = 0; stl < 4; ++stl){
      FragU a;
      const unsigned int* rp = &xsp[kb*4 + quad][stl*16 + ln];
      a.u.x = rp[0]; a.u.y = rp[2]; a.u.z = rp[4]; a.u.w = rp[6];
      #pragma unroll
      for (int gi = 0; gi < 4; ++gi)
        acc[stl][gi] = __builtin_amdgcn_mfma_f32_16x16x32_bf16(a.s, bcur[gi].s, acc[stl][gi], 0, 0, 0);
    }
    #pragma unroll
    for (int gi = 0; gi < 4; ++gi) bcur[gi] = bnxt[gi];
  }
  // ---- epilogue: LDS-staged, coalesced stores (two passes: d=0 then d=1)
  unsigned short* gl16 = (unsigned short*)&glb[0][0];   // row stride 136 u16
  for (int pass = 0; pass < 2; ++pass){
    if ((wv >> 1) == pass){
      #pragma unroll
      for (int stl = 0; stl < 4; ++stl)
        #pragma unroll
        for (int gi = 0; gi < 4; ++gi){
          int slot = gslot(g256[gi] & 127);
          #pragma unroll
          for (int r = 0; r < 4; ++r){
            int srow = stl*16 + quad*4 + r;     // 0..63 within half
            gl16[srow*136 + slot] = bfu(acc[stl][gi][r]);
          }
        }
    }
    __syncthreads();
    for (int q = threadIdx.x; q < 1024; q += 256){
      int srow = q >> 4, col = q & 15;
      int s = half*64 + srow;
      if (s < S_){
        uint4 v = *(const uint4*)(&glb[srow][col*4]);
        *(uint4*)(gx + ((size_t)(pass*N_ + n)*S_ + s)*G_ + col*8) = v;
      }
    }
    __syncthreads();
  }
}

// ---------------------------------------------------------------- fused LSTM stack + conv tail
__global__ __launch_bounds__(128)
__attribute__((amdgpu_waves_per_eu(1, 1)))
void k_mega(const unsigned short* __restrict__ gx,
    const float* __restrict__ whh0,           // [2,128,32]
    const unsigned short* __restrict__ wlb,   // [3,2,128,64] bf16
    const float* __restrict__ bih, const float* __restrict__ bhh,  // [3,2,128]
    const float* __restrict__ whh,            // [3,2,128,32]
    const unsigned short* __restrict__ wcv,   // [64,512] bf16, k-reversed
    const float* __restrict__ bct,
    const float* __restrict__ x,
    float* __restrict__ out){
  // LDS pool, 17280 dwords = 69120 B:
  //   rawA [0,4352)  rawB [4352,8704)  glds [8704,12928)  hsp [12928,17280)
  //   conv tail: hp2h [32][136] overlays rawA (final rin = rawB)
  __shared__ unsigned int smem[17280];
  unsigned int (*rawA)[68]     = (unsigned int (*)[68])smem;
  unsigned int (*rawB)[68]     = (unsigned int (*)[68])(smem + 4352);
  unsigned int (*glds)[32][66] = (unsigned int (*)[32][66])(smem + 8704);
  unsigned int (*hsp)[136]     = (unsigned int (*)[136])(smem + 12928);
  unsigned int (*hp2h)[136]    = (unsigned int (*)[136])smem;

  int n = blockIdx.x, b = n >> 7, f = n & 127;
  int tid = threadIdx.x;
  int lane = tid & 63, d = tid >> 6;
  int j = lane & 31, hi = lane >> 5;
  int ln = lane & 15, quad = lane >> 4;

  f32x2 w1[16], w2[16];
  float hv = 0.f, c = 0.f;
  unsigned int hgd[4];
  auto step = [&](unsigned int cur, int u){
    float gg1 = __uint_as_float(cur << 16);          // row lane     (i / f)
    float gg2 = __uint_as_float(cur & 0xffff0000u);  // row lane+64  (g / o)
    f32x2 A1 = {gg1, 0.f}, B1 = {0.f, 0.f};
    f32x2 A2 = {gg2, 0.f}, B2 = {0.f, 0.f};
    #pragma unroll
    for (int m = 0; m < 16; m += 2){
      f32x2 h0, h1;
      h0.x = __uint_as_float(__builtin_amdgcn_readlane(__float_as_uint(hv), 2*m));
      h0.y = __uint_as_float(__builtin_amdgcn_readlane(__float_as_uint(hv), 2*m+1));
      h1.x = __uint_as_float(__builtin_amdgcn_readlane(__float_as_uint(hv), 2*m+2));
      h1.y = __uint_as_float(__builtin_amdgcn_readlane(__float_as_uint(hv), 2*m+3));
      A1 += h0*w1[m];   A2 += h0*w2[m];
      B1 += h1*w1[m+1]; B2 += h1*w2[m+1];
    }
    float acc1 = (A1.x + B1.x) + (A1.y + B1.y);
    float acc2 = (A2.x + B2.x) + (A2.y + B2.y);
    float a1 = 1.f/(1.f + __expf(-acc1));            // sigmoid (i or f)
    float x2 = hi ? acc2 : 2.f*acc2;                 // shared-exp: o sigm / g tanh
    float tt = 1.f/(1.f + __expf(-x2));
    float a2 = hi ? tt : 2.f*tt - 1.f;
    ui2 p1 = __builtin_amdgcn_permlane32_swap(__float_as_uint(a1), __float_as_uint(a1), false, false);
    ui2 p2 = __builtin_amdgcn_permlane32_swap(__float_as_uint(a2), __float_as_uint(a2), false, false);
    float i_ = __uint_as_float(p1.x);   // low-half broadcast: i rows
    float f_ = __uint_as_float(p1.y);   // high-half broadcast: f rows
    float g_ = __uint_as_float(p2.x);   // low-half broadcast: g rows
    float o_ = __uint_as_float(p2.y);   // high-half broadcast: o rows
    c = f_*c + i_*g_;
    float tc = 1.f/(1.f + __expf(-2.f*c));
    hv = o_*(2.f*tc - 1.f);
    unsigned int hb = (unsigned int)bfu(hv);
    if ((u & 1) == 0) hgd[u >> 1] = hb;
    else              hgd[u >> 1] |= hb << 16;
  };
  auto loadw = [&](const float* wr1, const float* wr2){
    #pragma unroll
    for (int q = 0; q < 8; ++q){
      float4 aa = *(const float4*)(wr1 + q*4);
      float4 bb = *(const float4*)(wr2 + q*4);
      w1[q*2+0] = (f32x2){aa.x, aa.y}; w1[q*2+1] = (f32x2){aa.z, aa.w};
      w2[q*2+0] = (f32x2){bb.x, bb.y}; w2[q*2+1] = (f32x2){bb.z, bb.w};
    }
    #pragma unroll
    for (int k = 0; k < 16; ++k){             // pin weights (no sink/remat)
      asm volatile("" : "+v"(w1[k]));
      asm volatile("" : "+v"(w2[k]));
    }
  };

  // ---- layer 0 chain: gx (global) -> rawA
  {
    loadw(whh0 + (size_t)(d*G_ + lane)*H_, whh0 + (size_t)(d*G_ + lane + 64)*H_);
    const unsigned int* gxu = (const unsigned int*)gx;
    ptrdiff_t stride = d ? -64 : 64;
    const unsigned int* p0 = gxu + ((size_t)(d*N_ + n)*S_ + (d ? (S_-1) : 0))*64 + lane;
    unsigned short* hrow = (unsigned short*)&rawA[d*32 + j][0];
    unsigned int bufA[8], bufB[8];
    #pragma unroll
    for (int u = 0; u < 8; ++u) bufA[u] = p0[stride*u];
    for (int gg = 0; gg < 7; ++gg){
      int g0 = gg*2;
      #pragma unroll
      for (int u = 0; u < 8; ++u) bufB[u] = p0[stride*(8*(g0+1) + u)];
      #pragma unroll
      for (int u = 0; u < 8; ++u) step(bufA[u], u);
      if (!hi) *(uint4*)(hrow + 8*g0) = (uint4){hgd[0], hgd[1], hgd[2], hgd[3]};
      #pragma unroll
      for (int u = 0; u < 8; ++u) bufA[u] = p0[stride*(8*(g0+2) + u)];
      #pragma unroll
      for (int u = 0; u < 8; ++u) step(bufB[u], u);
      if (!hi) *(uint4*)(hrow + 8*(g0+1)) = (uint4){hgd[0], hgd[1], hgd[2], hgd[3]};
    }
    bufB[0] = p0[stride*120];
    #pragma unroll
    for (int u = 0; u < 8; ++u) step(bufA[u], u);
    if (!hi) *(uint4*)(hrow + 112) = (uint4){hgd[0], hgd[1], hgd[2], hgd[3]};
    step(bufB[0], 0);
    if (!hi) hrow[120] = (unsigned short)(hgd[0] & 0xffffu);
  }
  __syncthreads();

  // ---- layers 1..3
  unsigned int (*rin)[68]  = rawA;
  unsigned int (*rout)[68] = rawB;
  for (int l = 0; l < 3; ++l){
    // build hsp from rin (both waves cooperate)
    const unsigned short* rawu = (const unsigned short*)&rin[0][0];  // row stride 136 u16
    for (int i = tid; i < 32*128; i += 128){
      int srow = i >> 5, ip = i & 31;
      unsigned int v = 0;
      if (srow <= 120){
        int st = (ip < 16) ? srow : (120 - srow);
        v = (unsigned int)rawu[(2*ip)*136 + st] | ((unsigned int)rawu[(2*ip+1)*136 + st] << 16);
      }
      hsp[ip][srow] = v;
    }
    __syncthreads();

    const unsigned short* wp = wlb + (size_t)((l*2 + d)*G_)*64;
    float bias[8];
    const float* bip = bih + (size_t)(l*2 + d)*G_;
    const float* bhp = bhh + (size_t)(l*2 + d)*G_;
    #pragma unroll
    for (int gt = 0; gt < 8; ++gt) bias[gt] = bip[gt*16 + ln] + bhp[gt*16 + ln];
    loadw(whh + (size_t)((l*2 + d)*G_ + lane)*H_,
          whh + (size_t)((l*2 + d)*G_ + lane + 64)*H_);

    FragU bfrc[8][2];                        // per-layer B-fragments (hoisted)
    #pragma unroll
    for (int gt = 0; gt < 8; ++gt){
      bfrc[gt][0].u = *(const uint4*)(wp + (size_t)(gt*16 + ln)*64 + quad*8);
      bfrc[gt][1].u = *(const uint4*)(wp + (size_t)(gt*16 + ln)*64 + 32 + quad*8);
    }

    unsigned short* hrow = (unsigned short*)&rout[d*32 + j][0];
    const unsigned int* gr = &glds[d][0][lane];
    hv = 0.f; c = 0.f;

    for (int ch = 0; ch < 4; ++ch){
      int c0 = d ? (89 - 32*ch) : (32*ch);   // s-window base this chunk covers
      FragU af[2][2];
      #pragma unroll
      for (int stl = 0; stl < 2; ++stl){
        int srow = c0 + stl*16 + ln; if (srow < 0) srow = 0;   // junk rows unread
        #pragma unroll
        for (int kb = 0; kb < 2; ++kb){
          int ipb = kb*16 + quad*4;
          af[stl][kb].u.x = hsp[ipb+0][srow];
          af[stl][kb].u.y = hsp[ipb+1][srow];
          af[stl][kb].u.z = hsp[ipb+2][srow];
          af[stl][kb].u.w = hsp[ipb+3][srow];
        }
      }
      #pragma unroll
      for (int stl = 0; stl < 2; ++stl)
        #pragma unroll
        for (int gt2 = 0; gt2 < 4; ++gt2){
          f32x4 alo = (f32x4){bias[gt2],   bias[gt2],   bias[gt2],   bias[gt2]};
          f32x4 ahi = (f32x4){bias[gt2+4], bias[gt2+4], bias[gt2+4], bias[gt2+4]};
          alo = __builtin_amdgcn_mfma_f32_16x16x32_bf16(af[stl][0].s, bfrc[gt2  ][0].s, alo, 0, 0, 0);
          alo = __builtin_amdgcn_mfma_f32_16x16x32_bf16(af[stl][1].s, bfrc[gt2  ][1].s, alo, 0, 0, 0);
          ahi = __builtin_amdgcn_mfma_f32_16x16x32_bf16(af[stl][0].s, bfrc[gt2+4][0].s, ahi, 0, 0, 0);
          ahi = __builtin_amdgcn_mfma_f32_16x16x32_bf16(af[stl][1].s, bfrc[gt2+4][1].s, ahi, 0, 0, 0);
          #pragma unroll
          for (int r = 0; r < 4; ++r){
            int off = stl*16 + quad*4 + r;
            int ul = d ? (31 - off) : off;   // step-local row (d=1 flipped)
            glds[d][ul][gt2*16 + ln] = pk2(alo[r], ahi[r]);
          }
        }
      asm volatile("" ::: "memory");         // no ds_read hoists above the writes
      int nfull = (ch < 3) ? 4 : 3;
      for (int gq = 0; gq < nfull; ++gq){
        unsigned int bv[8];
        #pragma unroll
        for (int u = 0; u < 8; ++u) bv[u] = gr[(gq*8 + u)*66];
        #pragma unroll
        for (int u = 0; u < 8; ++u) step(bv[u], u);
        if (!hi) *(uint4*)(hrow + ch*32 + gq*8) = (uint4){hgd[0], hgd[1], hgd[2], hgd[3]};
      }
      if (ch == 3){
        unsigned int bv0 = gr[24*66];
        step(bv0, 0);
        if (!hi) hrow[120] = (unsigned short)(hgd[0] & 0xffffu);
      }
      asm volatile("" ::: "memory");         // next chunk's writes stay below these reads
    }
    __syncthreads();
    unsigned int (*t)[68] = rin; rin = rout; rout = t;
  }
  // final rin = rawB; rawA/glds/hsp now dead

  // ---- conv-transpose tail (was k_conv): rin -> out, two 32-ci passes
  {
    f32x4 ac[2][8];
    #pragma unroll
    for (int cg = 0; cg < 2; ++cg)
      #pragma unroll
      for (int nt = 0; nt < 8; ++nt) ac[cg][nt] = (f32x4){0.f,0.f,0.f,0.f};
    const unsigned short* wp0 = wcv + (size_t)(d*32 + ln)*512;
    const unsigned short* wp1 = wcv + (size_t)(d*32 + 16 + ln)*512;
    const unsigned short* rawu2 = (const unsigned short*)&rin[0][0];  // stride 136 u16
    for (int pass = 0; pass < 2; ++pass){
      // build hp2h for ci in [pass*32, pass*32+32)
      for (int it = tid; it < 32*136; it += 128){
        int cil = it / 136, col = it - cil*136;
        int ci = pass*32 + cil;
        int t0 = col - 8;
        int i0 = (ci < 32) ? t0 : (120 - t0);
        int i1 = (ci < 32) ? (t0+1) : (119 - t0);
        unsigned int lo  = (t0   >= 0 && t0   <= 120) ? rawu2[ci*136 + i0] : 0u;
        unsigned int hi2 = (t0+1 >= 0 && t0+1 <= 120) ? rawu2[ci*136 + i1] : 0u;
        hp2h[cil][col] = lo | (hi2 << 16);
      }
      __syncthreads();
      for (int kb = pass*8; kb < pass*8 + 8; ++kb){
        FragU a0, a1;
        a0.u = *(const uint4*)(wp0 + kb*32 + quad*8);
        a1.u = *(const uint4*)(wp1 + kb*32 + quad*8);
        int cil = (kb - pass*8)*4 + quad;
        #pragma unroll
        for (int nt = 0; nt < 8; ++nt){
          FragU bfr;
          const unsigned int* rp = &hp2h[cil][nt*16 + ln + 1];
          bfr.u.x = rp[0]; bfr.u.y = rp[2]; bfr.u.z = rp[4]; bfr.u.w = rp[6];
          ac[0][nt] = __builtin_amdgcn_mfma_f32_16x16x32_bf16(a0.s, bfr.s, ac[0][nt], 0, 0, 0);
          ac[1][nt] = __builtin_amdgcn_mfma_f32_16x16x32_bf16(a1.s, bfr.s, ac[1][nt], 0, 0, 0);
        }
      }
      __syncthreads();   // pass-0 reads complete before pass-1 overwrites hp2h
    }
    #pragma unroll
    for (int cg = 0; cg < 2; ++cg){
      float bb[4];
      #pragma unroll
      for (int r = 0; r < 4; ++r) bb[r] = bct[d*32 + cg*16 + quad*4 + r];
      #pragma unroll
      for (int nt = 0; nt < 8; ++nt)
        #pragma unroll
        for (int r = 0; r < 4; ++r){
          int co = d*32 + cg*16 + quad*4 + r, t = nt*16 + ln;
          size_t idx = ((size_t)(b*64 + co)*128 + f)*128 + t;
          out[idx] = ac[cg][nt][r] + bb[r] + x[idx];
        }
    }
  }
}

// ----------------------------------------------------------------
extern "C" void kernel_launch(void* const* d_in, const int* in_sizes, int n_in,
                              void* d_out, int out_size, void* d_ws, size_t ws_size,
                              hipStream_t stream){
  const float* x     = (const float*)d_in[0];
  const float* gamma = (const float*)d_in[1];
  const float* beta  = (const float*)d_in[2];
  const float* wih0  = (const float*)d_in[3];   // [2,128,512]
  const float* whh0  = (const float*)d_in[4];   // [2,128,32]
  const float* bih0  = (const float*)d_in[5];
  const float* bhh0  = (const float*)d_in[6];
  const float* wih   = (const float*)d_in[7];   // [3,2,128,64]
  const float* whh   = (const float*)d_in[8];   // [3,2,128,32]
  const float* bih   = (const float*)d_in[9];
  const float* bhh   = (const float*)d_in[10];
  const float* wct   = (const float*)d_in[11];  // [64,64,8]
  const float* bct   = (const float*)d_in[12];
  float* out = (float*)d_out;

  char* wsb = (char*)d_ws;
  float*          scale = (float*)(wsb);                       // 1 KB
  float*          shift = (float*)(wsb + 1024);                // 1 KB
  unsigned short* gx    = (unsigned short*)(wsb + 2048);       // 31,719,424 B (layer-0 gates)
  unsigned short* wb0   = (unsigned short*)(wsb + 48498688);   // 262,144 B
  unsigned short* wlb   = (unsigned short*)(wsb + 48760832);   // 98,304 B
  unsigned short* wcv   = (unsigned short*)(wsb + 48859136);   // 65,536 B

  k_norm<<<256, 256, 0, stream>>>(x, gamma, beta, scale, shift);
  k_wcvt<<<512, 256, 0, stream>>>(wih0, wb0, 2*G_*CK_);
  k_wcvt<<<192, 256, 0, stream>>>(wih,  wlb, 3*2*G_*64);
  k_wrev<<<128, 256, 0, stream>>>(wct,  wcv, 64*512);
  k_gx0 <<<1024, 256, 0, stream>>>(x, scale, shift, wb0, bih0, bhh0, gx);
  k_mega<<<512, 128, 0, stream>>>(gx, whh0, wlb, bih, bhh, whh, wcv, bct, x, out);
}

// Round 10
// 324.965 us; speedup vs baseline: 1.2571x; 1.0188x over previous
//
#include <hip/hip_runtime.h>

#define B_ 4
#define C_ 64
#define F_ 128
#define T_ 128
#define K_ 8
#define H_ 32
#define S_ 121   // T - K + 1
#define N_ 512   // B * F
#define G_ 128   // 4 * H
#define CK_ 512  // C * K

typedef __attribute__((ext_vector_type(8))) short short8;
typedef __attribute__((ext_vector_type(4))) float f32x4;
typedef __attribute__((ext_vector_type(2))) float f32x2;
typedef __attribute__((ext_vector_type(2))) unsigned int ui2;
union FragU { uint4 u; short8 s; };

__device__ __forceinline__ unsigned int pk2(float a, float b){   // RNE f32->bf16 pair
  unsigned int ua = __float_as_uint(a); ua += 0x7fffu + ((ua>>16)&1u);
  unsigned int ub = __float_as_uint(b); ub += 0x7fffu + ((ub>>16)&1u);
  return (ua>>16) | (ub & 0xffff0000u);
}
__device__ __forceinline__ unsigned short bfu(float a){          // RNE f32->bf16
  unsigned int ua = __float_as_uint(a); ua += 0x7fffu + ((ua>>16)&1u);
  return (unsigned short)(ua>>16);
}

// gx gate-pair interleaved slot: lane l of the chain reads one dword = (row l | row l+64 <<16)
__device__ __forceinline__ int gslot(int g){ return ((g & 63) << 1) | (g >> 6); }

// ---------------------------------------------------------------- fused prep: norm stats + weight conversions
// Round-15: one dispatch replaces k_norm + k_wcvt x2 + k_wrev (3 fewer launch gaps).
// Block ranges: [0,512) wb0 cvt, [512,704) wlb cvt, [704,832) wcv rev-cvt, [832,1088) norm.
__global__ __launch_bounds__(256) void k_prep(const float* __restrict__ x,
    const float* __restrict__ gamma, const float* __restrict__ beta,
    float* __restrict__ scale, float* __restrict__ shift,
    const float* __restrict__ wih0, unsigned short* __restrict__ wb0,
    const float* __restrict__ wih, unsigned short* __restrict__ wlb,
    const float* __restrict__ wct, unsigned short* __restrict__ wcv){
  int blk = blockIdx.x;
  if (blk < 512){
    int i = blk*256 + threadIdx.x;                 // 131072 = 512*256
    wb0[i] = bfu(wih0[i]);
  } else if (blk < 704){
    int i = (blk - 512)*256 + threadIdx.x;         // 49152 = 192*256
    wlb[i] = bfu(wih[i]);
  } else if (blk < 832){
    int i = (blk - 704)*256 + threadIdx.x;         // 32768 = 128*256
    int jx = (i & ~7) | (7 - (i & 7));
    wcv[i] = bfu(wct[jx]);
  } else {
    int bc = blk - 832;                            // 0..255
    const float* p = x + (size_t)bc * (F_*T_);
    float s = 0.f, q = 0.f;
    for (int i = threadIdx.x; i < F_*T_; i += 256){ float v = p[i]; s += v; q += v*v; }
    #pragma unroll
    for (int o = 32; o; o >>= 1){ s += __shfl_down(s, o); q += __shfl_down(q, o); }
    __shared__ float ss[4], qq[4];
    int w = threadIdx.x >> 6;
    if ((threadIdx.x & 63) == 0){ ss[w] = s; qq[w] = q; }
    __syncthreads();
    if (threadIdx.x == 0){
      s = ss[0]+ss[1]+ss[2]+ss[3]; q = qq[0]+qq[1]+qq[2]+qq[3];
      float mu  = s / (float)(F_*T_);
      float var = q / (float)(F_*T_) - mu*mu;
      if (var < 0.f) var = 0.f;
      int c = bc & (C_-1);
      float sc = gamma[c] * rsqrtf(var + 1e-5f);
      scale[bc] = sc;
      shift[bc] = beta[c] - mu * sc;
    }
  }
}

// ---------------------------------------------------------------- layer-0 projection, MFMA bf16
// Round-15: B-fragment prefetch depth 2 (3-slot rotation, statically unrolled) --
// the kb loop's serial L2-load->MFMA chain gets a full extra kb of cover.
__global__ __launch_bounds__(256) void k_gx0(const float* __restrict__ x,
    const float* __restrict__ scale, const float* __restrict__ shift,
    const unsigned short* __restrict__ wb0, const float* __restrict__ bi,
    const float* __restrict__ bh, unsigned short* __restrict__ gx){
  __shared__ unsigned int xsp[C_][80];      // packed bf16 pairs (t, t+1), local cols [0,72)
  __shared__ unsigned int glb[64][68];      // gate staging: [srow][128 u16 + pad], stride 136 u16
  int n = blockIdx.x >> 1, half = blockIdx.x & 1;
  int b = n >> 7, f = n & 127;
  const float* xb = x + (size_t)b*C_*F_*T_ + (size_t)f*T_;
  for (int i = threadIdx.x; i < C_*18; i += 256){
    int c = i / 18, q = i - c*18;
    int t0 = half*64 + q*4;
    float sc = scale[b*C_+c], sh = shift[b*C_+c];
    const float* xr = xb + (size_t)c*F_*T_;
    float4 v = (float4){0.f,0.f,0.f,0.f};
    float e = 0.f;
    bool in4 = (t0 < T_);
    if (in4) v = *(const float4*)(xr + t0);
    if (t0 + 4 < T_) e = xr[t0 + 4];
    float u0 = in4 ? v.x*sc+sh : 0.f;
    float u1 = in4 ? v.y*sc+sh : 0.f;
    float u2 = in4 ? v.z*sc+sh : 0.f;
    float u3 = in4 ? v.w*sc+sh : 0.f;
    float u4 = (t0+4 < T_) ? e*sc+sh : 0.f;
    unsigned int* xc = &xsp[c][q*4];
    xc[0] = pk2(u0,u1); xc[1] = pk2(u1,u2); xc[2] = pk2(u2,u3); xc[3] = pk2(u3,u4);
  }
  __syncthreads();
  int lane = threadIdx.x & 63, wv = threadIdx.x >> 6;
  int ln = lane & 15, quad = lane >> 4;
  int g256[4]; f32x4 acc[4][4];
  #pragma unroll
  for (int gi = 0; gi < 4; ++gi){
    g256[gi] = (wv*4 + gi)*16 + ln;
    float bv = bi[g256[gi]] + bh[g256[gi]];
    #pragma unroll
    for (int stl = 0; stl < 4; ++stl) acc[stl][gi] = (f32x4){bv, bv, bv, bv};
  }
  FragU bq0[4], bq1[4], bq2[4];
  #pragma unroll
  for (int gi = 0; gi < 4; ++gi){
    bq0[gi].u = *(const uint4*)(wb0 + (size_t)g256[gi]*CK_ + quad*8);
    bq1[gi].u = *(const uint4*)(wb0 + (size_t)g256[gi]*CK_ + 32 + quad*8);
  }
  #pragma unroll
  for (int kb = 0; kb < 16; ++kb){
    FragU* bu = (kb % 3 == 0) ? bq0 : (kb % 3 == 1) ? bq1 : bq2;
    FragU* bl = ((kb+2) % 3 == 0) ? bq0 : ((kb+2) % 3 == 1) ? bq1 : bq2;
    if (kb < 14){
      #pragma unroll
      for (int gi = 0; gi < 4; ++gi)
        bl[gi].u = *(const uint4*)(wb0 + (size_t)g256[gi]*CK_ + (kb+2)*32 + quad*8);
    }
    #pragma unroll
    for (int stl = 0; stl < 4; ++stl){
      FragU a;
      const unsigned int* rp = &xsp[kb*4 + quad][stl*16 + ln];
      a.u.x = rp[0]; a.u.y = rp[2]; a.u.z = rp[4]; a.u.w = rp[6];
      #pragma unroll
      for (int gi = 0; gi < 4; ++gi)
        acc[stl][gi] = __builtin_amdgcn_mfma_f32_16x16x32_bf16(a.s, bu[gi].s, acc[stl][gi], 0, 0, 0);
    }
  }
  // ---- epilogue: LDS-staged, coalesced stores (two passes: d=0 then d=1)
  unsigned short* gl16 = (unsigned short*)&glb[0][0];   // row stride 136 u16
  for (int pass = 0; pass < 2; ++pass){
    if ((wv >> 1) == pass){
      #pragma unroll
      for (int stl = 0; stl < 4; ++stl)
        #pragma unroll
        for (int gi = 0; gi < 4; ++gi){
          int slot = gslot(g256[gi] & 127);
          #pragma unroll
          for (int r = 0; r < 4; ++r){
            int srow = stl*16 + quad*4 + r;     // 0..63 within half
            gl16[srow*136 + slot] = bfu(acc[stl][gi][r]);
          }
        }
    }
    __syncthreads();
    for (int q = threadIdx.x; q < 1024; q += 256){
      int srow = q >> 4, col = q & 15;
      int s = half*64 + srow;
      if (s < S_){
        uint4 v = *(const uint4*)(&glb[srow][col*4]);
        *(uint4*)(gx + ((size_t)(pass*N_ + n)*S_ + s)*G_ + col*8) = v;
      }
    }
    __syncthreads();
  }
}

// ---------------------------------------------------------------- fused LSTM stack + conv tail
__global__ __launch_bounds__(128)
__attribute__((amdgpu_waves_per_eu(1, 1)))
void k_mega(const unsigned short* __restrict__ gx,
    const float* __restrict__ whh0,           // [2,128,32]
    const unsigned short* __restrict__ wlb,   // [3,2,128,64] bf16
    const float* __restrict__ bih, const float* __restrict__ bhh,  // [3,2,128]
    const float* __restrict__ whh,            // [3,2,128,32]
    const unsigned short* __restrict__ wcv,   // [64,512] bf16, k-reversed
    const float* __restrict__ bct,
    const float* __restrict__ x,
    float* __restrict__ out){
  // LDS pool, 17280 dwords = 69120 B:
  //   rawA [0,4352)  rawB [4352,8704)  glds [8704,12928)  hsp [12928,17280)
  //   conv tail: hp2h [32][136] overlays rawA (final rin = rawB)
  __shared__ unsigned int smem[17280];
  unsigned int (*rawA)[68]     = (unsigned int (*)[68])smem;
  unsigned int (*rawB)[68]     = (unsigned int (*)[68])(smem + 4352);
  unsigned int (*glds)[32][66] = (unsigned int (*)[32][66])(smem + 8704);
  unsigned int (*hsp)[136]     = (unsigned int (*)[136])(smem + 12928);
  unsigned int (*hp2h)[136]    = (unsigned int (*)[136])smem;

  int n = blockIdx.x, b = n >> 7, f = n & 127;
  int tid = threadIdx.x;
  int lane = tid & 63, d = tid >> 6;
  int j = lane & 31, hi = lane >> 5;
  int ln = lane & 15, quad = lane >> 4;

  f32x2 w1[16], w2[16];
  float hv = 0.f, c = 0.f;
  unsigned int hgd[4];
  auto step = [&](unsigned int cur, int u){
    float gg1 = __uint_as_float(cur << 16);          // row lane     (i / f)
    float gg2 = __uint_as_float(cur & 0xffff0000u);  // row lane+64  (g / o)
    f32x2 A1 = {gg1, 0.f}, B1 = {0.f, 0.f};
    f32x2 A2 = {gg2, 0.f}, B2 = {0.f, 0.f};
    #pragma unroll
    for (int m = 0; m < 16; m += 2){
      f32x2 h0, h1;
      h0.x = __uint_as_float(__builtin_amdgcn_readlane(__float_as_uint(hv), 2*m));
      h0.y = __uint_as_float(__builtin_amdgcn_readlane(__float_as_uint(hv), 2*m+1));
      h1.x = __uint_as_float(__builtin_amdgcn_readlane(__float_as_uint(hv), 2*m+2));
      h1.y = __uint_as_float(__builtin_amdgcn_readlane(__float_as_uint(hv), 2*m+3));
      A1 += h0*w1[m];   A2 += h0*w2[m];
      B1 += h1*w1[m+1]; B2 += h1*w2[m+1];
    }
    float acc1 = (A1.x + B1.x) + (A1.y + B1.y);
    float acc2 = (A2.x + B2.x) + (A2.y + B2.y);
    float a1 = 1.f/(1.f + __expf(-acc1));            // sigmoid (i or f)
    float x2 = hi ? acc2 : 2.f*acc2;                 // shared-exp: o sigm / g tanh
    float tt = 1.f/(1.f + __expf(-x2));
    float a2 = hi ? tt : 2.f*tt - 1.f;
    ui2 p1 = __builtin_amdgcn_permlane32_swap(__float_as_uint(a1), __float_as_uint(a1), false, false);
    ui2 p2 = __builtin_amdgcn_permlane32_swap(__float_as_uint(a2), __float_as_uint(a2), false, false);
    float i_ = __uint_as_float(p1.x);   // low-half broadcast: i rows
    float f_ = __uint_as_float(p1.y);   // high-half broadcast: f rows
    float g_ = __uint_as_float(p2.x);   // low-half broadcast: g rows
    float o_ = __uint_as_float(p2.y);   // high-half broadcast: o rows
    c = f_*c + i_*g_;
    float tc = 1.f/(1.f + __expf(-2.f*c));
    hv = o_*(2.f*tc - 1.f);
    unsigned int hb = (unsigned int)bfu(hv);
    if ((u & 1) == 0) hgd[u >> 1] = hb;
    else              hgd[u >> 1] |= hb << 16;
  };
  auto loadw = [&](const float* wr1, const float* wr2){
    #pragma unroll
    for (int q = 0; q < 8; ++q){
      float4 aa = *(const float4*)(wr1 + q*4);
      float4 bb = *(const float4*)(wr2 + q*4);
      w1[q*2+0] = (f32x2){aa.x, aa.y}; w1[q*2+1] = (f32x2){aa.z, aa.w};
      w2[q*2+0] = (f32x2){bb.x, bb.y}; w2[q*2+1] = (f32x2){bb.z, bb.w};
    }
    #pragma unroll
    for (int k = 0; k < 16; ++k){             // pin weights (no sink/remat)
      asm volatile("" : "+v"(w1[k]));
      asm volatile("" : "+v"(w2[k]));
    }
  };

  // ---- layer 0 chain: gx (global) -> rawA
  {
    loadw(whh0 + (size_t)(d*G_ + lane)*H_, whh0 + (size_t)(d*G_ + lane + 64)*H_);
    const unsigned int* gxu = (const unsigned int*)gx;
    ptrdiff_t stride = d ? -64 : 64;
    const unsigned int* p0 = gxu + ((size_t)(d*N_ + n)*S_ + (d ? (S_-1) : 0))*64 + lane;
    unsigned short* hrow = (unsigned short*)&rawA[d*32 + j][0];
    unsigned int bufA[8], bufB[8];
    #pragma unroll
    for (int u = 0; u < 8; ++u) bufA[u] = p0[stride*u];
    for (int gg = 0; gg < 7; ++gg){
      int g0 = gg*2;
      #pragma unroll
      for (int u = 0; u < 8; ++u) bufB[u] = p0[stride*(8*(g0+1) + u)];
      #pragma unroll
      for (int u = 0; u < 8; ++u) step(bufA[u], u);
      if (!hi) *(uint4*)(hrow + 8*g0) = (uint4){hgd[0], hgd[1], hgd[2], hgd[3]};
      #pragma unroll
      for (int u = 0; u < 8; ++u) bufA[u] = p0[stride*(8*(g0+2) + u)];
      #pragma unroll
      for (int u = 0; u < 8; ++u) step(bufB[u], u);
      if (!hi) *(uint4*)(hrow + 8*(g0+1)) = (uint4){hgd[0], hgd[1], hgd[2], hgd[3]};
    }
    bufB[0] = p0[stride*120];
    #pragma unroll
    for (int u = 0; u < 8; ++u) step(bufA[u], u);
    if (!hi) *(uint4*)(hrow + 112) = (uint4){hgd[0], hgd[1], hgd[2], hgd[3]};
    step(bufB[0], 0);
    if (!hi) hrow[120] = (unsigned short)(hgd[0] & 0xffffu);
  }
  __syncthreads();

  // ---- layers 1..3
  unsigned int (*rin)[68]  = rawA;
  unsigned int (*rout)[68] = rawB;
  for (int l = 0; l < 3; ++l){
    // build hsp from rin (both waves cooperate)
    const unsigned short* rawu = (const unsigned short*)&rin[0][0];  // row stride 136 u16
    for (int i = tid; i < 32*128; i += 128){
      int srow = i >> 5, ip = i & 31;
      unsigned int v = 0;
      if (srow <= 120){
        int st = (ip < 16) ? srow : (120 - srow);
        v = (unsigned int)rawu[(2*ip)*136 + st] | ((unsigned int)rawu[(2*ip+1)*136 + st] << 16);
      }
      hsp[ip][srow] = v;
    }
    __syncthreads();

    const unsigned short* wp = wlb + (size_t)((l*2 + d)*G_)*64;
    float bias[8];
    const float* bip = bih + (size_t)(l*2 + d)*G_;
    const float* bhp = bhh + (size_t)(l*2 + d)*G_;
    #pragma unroll
    for (int gt = 0; gt < 8; ++gt) bias[gt] = bip[gt*16 + ln] + bhp[gt*16 + ln];
    loadw(whh + (size_t)((l*2 + d)*G_ + lane)*H_,
          whh + (size_t)((l*2 + d)*G_ + lane + 64)*H_);

    FragU bfrc[8][2];                        // per-layer B-fragments (hoisted)
    #pragma unroll
    for (int gt = 0; gt < 8; ++gt){
      bfrc[gt][0].u = *(const uint4*)(wp + (size_t)(gt*16 + ln)*64 + quad*8);
      bfrc[gt][1].u = *(const uint4*)(wp + (size_t)(gt*16 + ln)*64 + 32 + quad*8);
    }

    unsigned short* hrow = (unsigned short*)&rout[d*32 + j][0];
    const unsigned int* gr = &glds[d][0][lane];
    hv = 0.f; c = 0.f;

    for (int ch = 0; ch < 4; ++ch){
      int c0 = d ? (89 - 32*ch) : (32*ch);   // s-window base this chunk covers
      FragU af[2][2];
      #pragma unroll
      for (int stl = 0; stl < 2; ++stl){
        int srow = c0 + stl*16 + ln; if (srow < 0) srow = 0;   // junk rows unread
        #pragma unroll
        for (int kb = 0; kb < 2; ++kb){
          int ipb = kb*16 + quad*4;
          af[stl][kb].u.x = hsp[ipb+0][srow];
          af[stl][kb].u.y = hsp[ipb+1][srow];
          af[stl][kb].u.z = hsp[ipb+2][srow];
          af[stl][kb].u.w = hsp[ipb+3][srow];
        }
      }
      #pragma unroll
      for (int stl = 0; stl < 2; ++stl)
        #pragma unroll
        for (int gt2 = 0; gt2 < 4; ++gt2){
          f32x4 alo = (f32x4){bias[gt2],   bias[gt2],   bias[gt2],   bias[gt2]};
          f32x4 ahi = (f32x4){bias[gt2+4], bias[gt2+4], bias[gt2+4], bias[gt2+4]};
          alo = __builtin_amdgcn_mfma_f32_16x16x32_bf16(af[stl][0].s, bfrc[gt2  ][0].s, alo, 0, 0, 0);
          alo = __builtin_amdgcn_mfma_f32_16x16x32_bf16(af[stl][1].s, bfrc[gt2  ][1].s, alo, 0, 0, 0);
          ahi = __builtin_amdgcn_mfma_f32_16x16x32_bf16(af[stl][0].s, bfrc[gt2+4][0].s, ahi, 0, 0, 0);
          ahi = __builtin_amdgcn_mfma_f32_16x16x32_bf16(af[stl][1].s, bfrc[gt2+4][1].s, ahi, 0, 0, 0);
          #pragma unroll
          for (int r = 0; r < 4; ++r){
            int off = stl*16 + quad*4 + r;
            int ul = d ? (31 - off) : off;   // step-local row (d=1 flipped)
            glds[d][ul][gt2*16 + ln] = pk2(alo[r], ahi[r]);
          }
        }
      asm volatile("" ::: "memory");         // no ds_read hoists above the writes
      int nfull = (ch < 3) ? 4 : 3;
      for (int gq = 0; gq < nfull; ++gq){
        unsigned int bv[8];
        #pragma unroll
        for (int u = 0; u < 8; ++u) bv[u] = gr[(gq*8 + u)*66];
        #pragma unroll
        for (int u = 0; u < 8; ++u) step(bv[u], u);
        if (!hi) *(uint4*)(hrow + ch*32 + gq*8) = (uint4){hgd[0], hgd[1], hgd[2], hgd[3]};
      }
      if (ch == 3){
        unsigned int bv0 = gr[24*66];
        step(bv0, 0);
        if (!hi) hrow[120] = (unsigned short)(hgd[0] & 0xffffu);
      }
      asm volatile("" ::: "memory");         // next chunk's writes stay below these reads
    }
    __syncthreads();
    unsigned int (*t)[68] = rin; rin = rout; rout = t;
  }
  // final rin = rawB; rawA/glds/hsp now dead

  // ---- conv-transpose tail (was k_conv): rin -> out, two 32-ci passes
  {
    f32x4 ac[2][8];
    #pragma unroll
    for (int cg = 0; cg < 2; ++cg)
      #pragma unroll
      for (int nt = 0; nt < 8; ++nt) ac[cg][nt] = (f32x4){0.f,0.f,0.f,0.f};
    const unsigned short* wp0 = wcv + (size_t)(d*32 + ln)*512;
    const unsigned short* wp1 = wcv + (size_t)(d*32 + 16 + ln)*512;
    const unsigned short* rawu2 = (const unsigned short*)&rin[0][0];  // stride 136 u16
    for (int pass = 0; pass < 2; ++pass){
      // build hp2h for ci in [pass*32, pass*32+32)
      for (int it = tid; it < 32*136; it += 128){
        int cil = it / 136, col = it - cil*136;
        int ci = pass*32 + cil;
        int t0 = col - 8;
        int i0 = (ci < 32) ? t0 : (120 - t0);
        int i1 = (ci < 32) ? (t0+1) : (119 - t0);
        unsigned int lo  = (t0   >= 0 && t0   <= 120) ? rawu2[ci*136 + i0] : 0u;
        unsigned int hi2 = (t0+1 >= 0 && t0+1 <= 120) ? rawu2[ci*136 + i1] : 0u;
        hp2h[cil][col] = lo | (hi2 << 16);
      }
      __syncthreads();
      for (int kb = pass*8; kb < pass*8 + 8; ++kb){
        FragU a0, a1;
        a0.u = *(const uint4*)(wp0 + kb*32 + quad*8);
        a1.u = *(const uint4*)(wp1 + kb*32 + quad*8);
        int cil = (kb - pass*8)*4 + quad;
        #pragma unroll
        for (int nt = 0; nt < 8; ++nt){
          FragU bfr;
          const unsigned int* rp = &hp2h[cil][nt*16 + ln + 1];
          bfr.u.x = rp[0]; bfr.u.y = rp[2]; bfr.u.z = rp[4]; bfr.u.w = rp[6];
          ac[0][nt] = __builtin_amdgcn_mfma_f32_16x16x32_bf16(a0.s, bfr.s, ac[0][nt], 0, 0, 0);
          ac[1][nt] = __builtin_amdgcn_mfma_f32_16x16x32_bf16(a1.s, bfr.s, ac[1][nt], 0, 0, 0);
        }
      }
      __syncthreads();   // pass-0 reads complete before pass-1 overwrites hp2h
    }
    #pragma unroll
    for (int cg = 0; cg < 2; ++cg){
      float bb[4];
      #pragma unroll
      for (int r = 0; r < 4; ++r) bb[r] = bct[d*32 + cg*16 + quad*4 + r];
      #pragma unroll
      for (int nt = 0; nt < 8; ++nt)
        #pragma unroll
        for (int r = 0; r < 4; ++r){
          int co = d*32 + cg*16 + quad*4 + r, t = nt*16 + ln;
          size_t idx = ((size_t)(b*64 + co)*128 + f)*128 + t;
          out[idx] = ac[cg][nt][r] + bb[r] + x[idx];
        }
    }
  }
}

// ----------------------------------------------------------------
extern "C" void kernel_launch(void* const* d_in, const int* in_sizes, int n_in,
                              void* d_out, int out_size, void* d_ws, size_t ws_size,
                              hipStream_t stream){
  const float* x     = (const float*)d_in[0];
  const float* gamma = (const float*)d_in[1];
  const float* beta  = (const float*)d_in[2];
  const float* wih0  = (const float*)d_in[3];   // [2,128,512]
  const float* whh0  = (const float*)d_in[4];   // [2,128,32]
  const float* bih0  = (const float*)d_in[5];
  const float* bhh0  = (const float*)d_in[6];
  const float* wih   = (const float*)d_in[7];   // [3,2,128,64]
  const float* whh   = (const float*)d_in[8];   // [3,2,128,32]
  const float* bih   = (const float*)d_in[9];
  const float* bhh   = (const float*)d_in[10];
  const float* wct   = (const float*)d_in[11];  // [64,64,8]
  const float* bct   = (const float*)d_in[12];
  float* out = (float*)d_out;

  char* wsb = (char*)d_ws;
  float*          scale = (float*)(wsb);                       // 1 KB
  float*          shift = (float*)(wsb + 1024);                // 1 KB
  unsigned short* gx    = (unsigned short*)(wsb + 2048);       // 31,719,424 B (layer-0 gates)
  unsigned short* wb0   = (unsigned short*)(wsb + 48498688);   // 262,144 B
  unsigned short* wlb   = (unsigned short*)(wsb + 48760832);   // 98,304 B
  unsigned short* wcv   = (unsigned short*)(wsb + 48859136);   // 65,536 B

  k_prep<<<1088, 256, 0, stream>>>(x, gamma, beta, scale, shift,
                                   wih0, wb0, wih, wlb, wct, wcv);
  k_gx0 <<<1024, 256, 0, stream>>>(x, scale, shift, wb0, bih0, bhh0, gx);
  k_mega<<<512, 128, 0, stream>>>(gx, whh0, wlb, bih, bhh, whh, wcv, bct, x, out);
}